// Round 9
// baseline (895.960 us; speedup 1.0000x reference)
//
#include <hip/hip_runtime.h>
#include <stdint.h>

// ---------------------------------------------------------------------------
// GraphSAGE(min) x3 + BatchNorm + ReLU + log_softmax, fp32, MI355X (gfx950)
//
// R5: dst-major CSR + dst-range fill; BN fused into consumers. (404us)
// R7: register-tiled k_gemm64t (64-node tile, 4x4 acc/lane, one sync).
// R8: fix R7 bug — weight staging loop wrote 4096 float4 into a 1024-float4
//     LDS array (i<16 instead of i<4), trampling sWr/rowA/rowX and reading
//     past Wl. Loops corrected to i<4 (4 x 256thr x 16B = 16KB exactly).
// ---------------------------------------------------------------------------

#define NG 8  // dst-range groups for fill (== XCDs)

__device__ __forceinline__ float bnrelu1(float v, float mu, float is, float g, float b) {
    return fmaxf((v - mu) * is * g + b, 0.0f);
}

// ---------------------------------------------------------------------------
// zero deg + detect edge dtype (int64 => odd int32 slots all zero)
__global__ __launch_bounds__(256)
void k_prep(int* __restrict__ deg, int n_nodes, const int* __restrict__ ei32,
            int* __restrict__ flag) {
    int i = blockIdx.x * blockDim.x + threadIdx.x;
    int stride = gridDim.x * blockDim.x;
    for (int j = i; j < n_nodes; j += stride) deg[j] = 0;
    if (i == 0) {
        int allzero = 1;
        for (int t = 1; t < 32; t += 2) allzero &= (ei32[t] == 0);
        *flag = allzero;
    }
}

// ---------------------------------------------------------------------------
// edge_index -> int32 src/dst + degree histogram in one pass
__global__ __launch_bounds__(256)
void k_convert_hist(const void* __restrict__ ei, int n_edges,
                    const int* __restrict__ flag, int* __restrict__ src32,
                    int* __restrict__ dst32, int* __restrict__ deg) {
    const bool is64 = (*flag != 0);
    const int* e32 = (const int*)ei;
    const long long* e64 = (const long long*)ei;
    int i = blockIdx.x * blockDim.x + threadIdx.x;
    int stride = gridDim.x * blockDim.x;
    for (int e = i; e < n_edges; e += stride) {
        int s, d;
        if (is64) { s = (int)e64[e]; d = (int)e64[n_edges + e]; }
        else      { s = e32[e];      d = e32[n_edges + e]; }
        src32[e] = s;
        dst32[e] = d;
        atomicAdd(&deg[d], 1);
    }
}

// ---------------------------------------------------------------------------
// hierarchical scan
__global__ __launch_bounds__(256)
void k_scan1(const int* __restrict__ deg, int* __restrict__ bsum, int n) {
    __shared__ int red[256];
    const int t = threadIdx.x;
    const int i = blockIdx.x * 256 + t;
    red[t] = (i < n) ? deg[i] : 0;
    __syncthreads();
    for (int off = 128; off; off >>= 1) {
        if (t < off) red[t] += red[t + off];
        __syncthreads();
    }
    if (t == 0) bsum[blockIdx.x] = red[0];
}

__global__ __launch_bounds__(1024)
void k_scan2(const int* __restrict__ bsum, int* __restrict__ boffs,
             int nb, int* __restrict__ rowptr, int n) {
    __shared__ int part[1024];
    const int t = threadIdx.x;
    part[t] = (t < nb) ? bsum[t] : 0;
    __syncthreads();
    for (int off = 1; off < 1024; off <<= 1) {
        int v = (t >= off) ? part[t - off] : 0;
        __syncthreads();
        part[t] += v;
        __syncthreads();
    }
    if (t < nb) boffs[t] = (t == 0) ? 0 : part[t - 1];
    if (t == 0) rowptr[n] = part[nb - 1];
}

__global__ __launch_bounds__(256)
void k_scan3(const int* __restrict__ deg, const int* __restrict__ boffs,
             int* __restrict__ rowptr, int* __restrict__ cursor, int n) {
    __shared__ int part[256];
    const int t = threadIdx.x;
    const int i = blockIdx.x * 256 + t;
    const int d = (i < n) ? deg[i] : 0;
    part[t] = d;
    __syncthreads();
    for (int off = 1; off < 256; off <<= 1) {
        int v = (t >= off) ? part[t - off] : 0;
        __syncthreads();
        part[t] += v;
        __syncthreads();
    }
    if (i < n) {
        int excl = boffs[blockIdx.x] + part[t] - d;
        rowptr[i] = excl;
        cursor[i] = excl;
    }
}

// ---------------------------------------------------------------------------
// dst-range-partitioned fill: group g's csr writes land in one contiguous
// XCD-local region; CSR layout stays dst-major for the consumer.
__global__ __launch_bounds__(256)
void k_fill_r(const int* __restrict__ src32, const int* __restrict__ dst32,
              int n_edges, int* __restrict__ cursor, int* __restrict__ csr,
              int NN, int blocks_per_group) {
    const int g = blockIdx.x & (NG - 1);
    const int jb = blockIdx.x >> 3;
    const int lo = (int)((long long)g * NN / NG);
    const int hi = (int)((long long)(g + 1) * NN / NG);
    const int stride = blocks_per_group * 256;
    for (int e = jb * 256 + threadIdx.x; e < n_edges; e += stride) {
        int d = dst32[e];
        if (d >= lo && d < hi) {
            int pos = atomicAdd(&cursor[d], 1);
            csr[pos] = src32[e];
        }
    }
}

// ---------------------------------------------------------------------------
// one wave per dst node, lane = channel; single segment, 4 gathers in flight.
template <bool BN>
__global__ __launch_bounds__(256)
void k_agg(const float* __restrict__ x, const int* __restrict__ rowptr,
           const int* __restrict__ csr, float* __restrict__ agg, int NN,
           const float* __restrict__ mu, const float* __restrict__ istd,
           const float* __restrict__ gam, const float* __restrict__ bet) {
    const int lane = threadIdx.x & 63;
    const int wave = (blockIdx.x * blockDim.x + threadIdx.x) >> 6;
    const int nwaves = (gridDim.x * blockDim.x) >> 6;
    float s_mu = 0.f, s_is = 0.f, s_g = 0.f, s_b = 0.f;
    if (BN) { s_mu = mu[lane]; s_is = istd[lane]; s_g = gam[lane]; s_b = bet[lane]; }
    for (int n = wave; n < NN; n += nwaves) {
        const int beg = rowptr[n], end = rowptr[n + 1];
        float m = __builtin_inff();
        int e = beg;
        for (; e + 4 <= end; e += 4) {
            int s0 = csr[e], s1 = csr[e + 1], s2 = csr[e + 2], s3 = csr[e + 3];
            float v0 = x[(size_t)s0 * 64 + lane];
            float v1 = x[(size_t)s1 * 64 + lane];
            float v2 = x[(size_t)s2 * 64 + lane];
            float v3 = x[(size_t)s3 * 64 + lane];
            if (BN) {
                v0 = bnrelu1(v0, s_mu, s_is, s_g, s_b);
                v1 = bnrelu1(v1, s_mu, s_is, s_g, s_b);
                v2 = bnrelu1(v2, s_mu, s_is, s_g, s_b);
                v3 = bnrelu1(v3, s_mu, s_is, s_g, s_b);
            }
            m = fminf(m, fminf(fminf(v0, v1), fminf(v2, v3)));
        }
        for (; e < end; ++e) {
            float v = x[(size_t)csr[e] * 64 + lane];
            if (BN) v = bnrelu1(v, s_mu, s_is, s_g, s_b);
            m = fminf(m, v);
        }
        agg[(size_t)n * 64 + lane] = (end > beg) ? m : 0.0f;
    }
}

// ---------------------------------------------------------------------------
// register-tiled 64->64 GEMM: 64-node block, lane = (cg, ng), acc[4 nodes][4 ch].
template <bool BNX>
__global__ __launch_bounds__(256)
void k_gemm64t(const float* __restrict__ agg, const float* __restrict__ xin,
               const float* __restrict__ Wl, const float* __restrict__ bl,
               const float* __restrict__ Wr, float* __restrict__ hout,
               float* __restrict__ psum, float* __restrict__ psq, int NN,
               const float* __restrict__ mu, const float* __restrict__ istd,
               const float* __restrict__ gam, const float* __restrict__ bet) {
    __shared__ float sWl[64][64];        // k-major, as input
    __shared__ float sWr[64][64];
    __shared__ float rowA[64][68];       // pad 68: ng groups hit distinct banks
    __shared__ float rowX[64][68];
    __shared__ float4 red4[4][64];
    const int t = threadIdx.x;
    // ---- stage weights: 64x64 f = 1024 float4 = 4 iters x 256 thr ----
#pragma unroll
    for (int i = 0; i < 4; ++i) {
        int id = i * 256 + t;
        ((float4*)sWl)[id] = ((const float4*)Wl)[id];
        ((float4*)sWr)[id] = ((const float4*)Wr)[id];
    }
    // ---- stage rows: 64 nodes x 16 float4 = 1024 float4 ----
    const int base = blockIdx.x * 64;
#pragma unroll
    for (int i = 0; i < 4; ++i) {
        int id = i * 256 + t;
        int n = id >> 4, s = id & 15;
        int gn = base + n;
        float4 a4 = {0.f, 0.f, 0.f, 0.f};
        float4 x4 = {0.f, 0.f, 0.f, 0.f};
        if (gn < NN) {
            a4 = *(const float4*)&agg[(size_t)gn * 64 + s * 4];
            x4 = *(const float4*)&xin[(size_t)gn * 64 + s * 4];
            if (BNX) {
                const float4 m4 = *(const float4*)&mu[s * 4];
                const float4 i4 = *(const float4*)&istd[s * 4];
                const float4 g4 = *(const float4*)&gam[s * 4];
                const float4 b4 = *(const float4*)&bet[s * 4];
                x4.x = bnrelu1(x4.x, m4.x, i4.x, g4.x, b4.x);
                x4.y = bnrelu1(x4.y, m4.y, i4.y, g4.y, b4.y);
                x4.z = bnrelu1(x4.z, m4.z, i4.z, g4.z, b4.z);
                x4.w = bnrelu1(x4.w, m4.w, i4.w, g4.w, b4.w);
            }
        }
        *(float4*)&rowA[n][s * 4] = a4;
        *(float4*)&rowX[n][s * 4] = x4;
    }
    __syncthreads();
    // ---- compute: wave w covers nodes w*16..w*16+15 ----
    const int lane = t & 63, w = t >> 6;
    const int cg = lane & 15, ng = lane >> 4;
    const int c0 = cg * 4;
    const int nb = w * 16 + ng * 4;
    float4 acc[4];
#pragma unroll
    for (int j = 0; j < 4; ++j) acc[j] = {0.f, 0.f, 0.f, 0.f};
#pragma unroll
    for (int k = 0; k < 64; ++k) {
        const float4 wl4 = *(const float4*)&sWl[k][c0];  // 2-way alias: free
        const float4 wr4 = *(const float4*)&sWr[k][c0];
#pragma unroll
        for (int j = 0; j < 4; ++j) {
            const float a = rowA[nb + j][k];  // broadcast within cg group
            const float xv = rowX[nb + j][k];
            acc[j].x = fmaf(a, wl4.x, acc[j].x);
            acc[j].y = fmaf(a, wl4.y, acc[j].y);
            acc[j].z = fmaf(a, wl4.z, acc[j].z);
            acc[j].w = fmaf(a, wl4.w, acc[j].w);
            acc[j].x = fmaf(xv, wr4.x, acc[j].x);
            acc[j].y = fmaf(xv, wr4.y, acc[j].y);
            acc[j].z = fmaf(xv, wr4.z, acc[j].z);
            acc[j].w = fmaf(xv, wr4.w, acc[j].w);
        }
    }
    const float4 bc4 = *(const float4*)&bl[c0];
    float4 ls = {0.f, 0.f, 0.f, 0.f};
    float4 lq = {0.f, 0.f, 0.f, 0.f};
#pragma unroll
    for (int j = 0; j < 4; ++j) {
        const int gn = base + nb + j;
        if (gn < NN) {
            float4 h;
            h.x = bc4.x + acc[j].x;
            h.y = bc4.y + acc[j].y;
            h.z = bc4.z + acc[j].z;
            h.w = bc4.w + acc[j].w;
            *(float4*)&hout[(size_t)gn * 64 + c0] = h;
            ls.x += h.x; ls.y += h.y; ls.z += h.z; ls.w += h.w;
            lq.x = fmaf(h.x, h.x, lq.x);
            lq.y = fmaf(h.y, h.y, lq.y);
            lq.z = fmaf(h.z, h.z, lq.z);
            lq.w = fmaf(h.w, h.w, lq.w);
        }
    }
    // ---- per-block stats: channel c held by lanes (cg=c>>2, comp=c&3) ----
    red4[w][lane] = ls;
    __syncthreads();
    if (t < 64) {
        const int rcg = t >> 2, comp = t & 3;
        float S = 0.f;
#pragma unroll
        for (int ww = 0; ww < 4; ++ww)
#pragma unroll
            for (int g = 0; g < 4; ++g)
                S += ((const float*)&red4[ww][g * 16 + rcg])[comp];
        psum[(size_t)blockIdx.x * 64 + t] = S;
    }
    __syncthreads();
    red4[w][lane] = lq;
    __syncthreads();
    if (t < 64) {
        const int rcg = t >> 2, comp = t & 3;
        float S = 0.f;
#pragma unroll
        for (int ww = 0; ww < 4; ++ww)
#pragma unroll
            for (int g = 0; g < 4; ++g)
                S += ((const float*)&red4[ww][g * 16 + rcg])[comp];
        psq[(size_t)blockIdx.x * 64 + t] = S;
    }
}

// ---------------------------------------------------------------------------
// float-slot finalize: 1024 thr = 16 groups x 64 ch; double accumulation.
__global__ __launch_bounds__(1024)
void k_finalize(const float* __restrict__ psum, const float* __restrict__ psq,
                float* __restrict__ mu, float* __restrict__ istd,
                int n_nodes, int nblocks) {
    __shared__ double s_s[16][64];
    __shared__ double s_q[16][64];
    const int t = threadIdx.x;
    const int c = t & 63, g = t >> 6;
    double s = 0.0, q = 0.0;
    for (int b = g; b < nblocks; b += 16) {
        s += (double)psum[(size_t)b * 64 + c];
        q += (double)psq[(size_t)b * 64 + c];
    }
    s_s[g][c] = s;
    s_q[g][c] = q;
    __syncthreads();
    if (g == 0) {
        double S = 0.0, Q = 0.0;
#pragma unroll
        for (int i = 0; i < 16; ++i) { S += s_s[i][c]; Q += s_q[i][c]; }
        double m = S / n_nodes;
        double var = Q / n_nodes - m * m;
        mu[c] = (float)m;
        istd[c] = (float)(1.0 / sqrt(var + 1e-5));
    }
}

// ---------------------------------------------------------------------------
// 64->16 GEMM + log_softmax. Block = 16 nodes x 16 ch; BN on xin inline.
__global__ __launch_bounds__(256)
void k_l3(const float* __restrict__ agg, const float* __restrict__ xin,
          const float* __restrict__ W3l, const float* __restrict__ b3,
          const float* __restrict__ W3r, float* __restrict__ out, int n_nodes,
          const float* __restrict__ mu, const float* __restrict__ istd,
          const float* __restrict__ gam, const float* __restrict__ bet) {
    __shared__ float sWl[64][16];
    __shared__ float sWr[64][16];
    __shared__ float rowA[16][65];
    __shared__ float rowX[16][65];
    const int t = threadIdx.x;
    for (int i = t; i < 1024; i += 256) {
        ((float*)sWl)[i] = W3l[i];
        ((float*)sWr)[i] = W3r[i];
    }
    const int kc = t & 63;
    const float s_mu = mu[kc], s_is = istd[kc], s_g = gam[kc], s_b = bet[kc];
    const int base = blockIdx.x * 16;
#pragma unroll
    for (int i = 0; i < 4; ++i) {
        int j = t + i * 256;
        int nd = j >> 6, k = j & 63;
        int gnode = base + nd;
        if (gnode < n_nodes) {
            rowA[nd][k] = agg[(size_t)gnode * 64 + k];
            rowX[nd][k] = bnrelu1(xin[(size_t)gnode * 64 + k], s_mu, s_is, s_g, s_b);
        } else {
            rowA[nd][k] = 0.0f;
            rowX[nd][k] = 0.0f;
        }
    }
    __syncthreads();
    const int n = t >> 4, c = t & 15;
    float acc = b3[c];
#pragma unroll
    for (int k = 0; k < 64; ++k)
        acc = fmaf(rowA[n][k], sWl[k][c], fmaf(rowX[n][k], sWr[k][c], acc));
    float m = acc;
    for (int off = 8; off; off >>= 1) m = fmaxf(m, __shfl_xor(m, off, 16));
    float ex = expf(acc - m);
    float ssum = ex;
    for (int off = 8; off; off >>= 1) ssum += __shfl_xor(ssum, off, 16);
    if (base + n < n_nodes)
        out[(size_t)(base + n) * 16 + c] = (acc - m) - logf(ssum);
}

// ---------------------------------------------------------------------------
extern "C" void kernel_launch(void* const* d_in, const int* in_sizes, int n_in,
                              void* d_out, int out_size, void* d_ws, size_t ws_size,
                              hipStream_t stream) {
    (void)n_in; (void)out_size; (void)ws_size;
    const float* x   = (const float*)d_in[0];
    const void*  ei  = d_in[1];
    const float* W1l = (const float*)d_in[2];
    const float* b1  = (const float*)d_in[3];
    const float* W1r = (const float*)d_in[4];
    const float* g1  = (const float*)d_in[5];
    const float* be1 = (const float*)d_in[6];
    const float* W2l = (const float*)d_in[7];
    const float* b2  = (const float*)d_in[8];
    const float* W2r = (const float*)d_in[9];
    const float* g2  = (const float*)d_in[10];
    const float* be2 = (const float*)d_in[11];
    const float* W3l = (const float*)d_in[12];
    const float* b3  = (const float*)d_in[13];
    const float* W3r = (const float*)d_in[14];
    float* out = (float*)d_out;

    const int NN = in_sizes[0] / 64;
    const int n_edges = in_sizes[1] / 2;
    const int nAgg = NN * 64;

    size_t off = 0;
    auto alloc = [&](size_t bytes) {
        void* p = (char*)d_ws + off;
        off = (off + bytes + 255) & ~(size_t)255;
        return p;
    };
    float* agg    = (float*)alloc((size_t)nAgg * 4);
    float* hA     = (float*)alloc((size_t)nAgg * 4);
    float* hB     = (float*)alloc((size_t)nAgg * 4);
    int*   csr    = (int*)  alloc((size_t)n_edges * 4);
    int*   src32  = (int*)  alloc((size_t)n_edges * 4);
    int*   dst32  = (int*)  alloc((size_t)n_edges * 4);
    int*   rowptr = (int*)  alloc((size_t)(NN + 1) * 4);
    int*   cursor = (int*)  alloc((size_t)NN * 4);
    int*   deg    = (int*)  alloc((size_t)NN * 4);
    int*   bsum   = (int*)  alloc(1024 * 4);
    int*   boffs  = (int*)  alloc(1024 * 4);
    const int NB64 = (NN + 63) / 64;  // 782 gemm blocks
    float* psum   = (float*)alloc((size_t)NB64 * 64 * 4);
    float* psq    = (float*)alloc((size_t)NB64 * 64 * 4);
    float* mu1    = (float*)alloc(64 * 4);
    float* istd1  = (float*)alloc(64 * 4);
    float* mu2    = (float*)alloc(64 * 4);
    float* istd2  = (float*)alloc(64 * 4);
    int*   flag   = (int*)  alloc(4);

    const int GHF = 1024;             // fill: 8 groups x 128 blocks
    const int BPG = GHF / NG;
    const int NB = (NN + 255) / 256;  // 196 <= 1024
    const int GA = 2048;
    const int GL3 = (NN + 15) / 16;

    // ---- build CSR once ----
    k_prep        <<<256, 256, 0, stream>>>(deg, NN, (const int*)ei, flag);
    k_convert_hist<<<1024, 256, 0, stream>>>(ei, n_edges, flag, src32, dst32, deg);
    k_scan1       <<<NB, 256, 0, stream>>>(deg, bsum, NN);
    k_scan2       <<<1, 1024, 0, stream>>>(bsum, boffs, NB, rowptr, NN);
    k_scan3       <<<NB, 256, 0, stream>>>(deg, boffs, rowptr, cursor, NN);
    k_fill_r      <<<GHF, 256, 0, stream>>>(src32, dst32, n_edges, cursor, csr, NN, BPG);

    // ---- layer 1 ----
    k_agg<false><<<GA, 256, 0, stream>>>(x, rowptr, csr, agg, NN,
                                         nullptr, nullptr, nullptr, nullptr);
    k_gemm64t<false><<<NB64, 256, 0, stream>>>(agg, x, W1l, b1, W1r, hA,
                                               psum, psq, NN,
                                               nullptr, nullptr, nullptr, nullptr);
    k_finalize<<<1, 1024, 0, stream>>>(psum, psq, mu1, istd1, NN, NB64);
    // ---- layer 2 (BN1 fused into consumers) ----
    k_agg<true><<<GA, 256, 0, stream>>>(hA, rowptr, csr, agg, NN, mu1, istd1, g1, be1);
    k_gemm64t<true><<<NB64, 256, 0, stream>>>(agg, hA, W2l, b2, W2r, hB,
                                              psum, psq, NN, mu1, istd1, g1, be1);
    k_finalize<<<1, 1024, 0, stream>>>(psum, psq, mu2, istd2, NN, NB64);
    // ---- layer 3 (BN2 fused into consumers) + log_softmax ----
    k_agg<true><<<GA, 256, 0, stream>>>(hB, rowptr, csr, agg, NN, mu2, istd2, g2, be2);
    k_l3<<<GL3, 256, 0, stream>>>(agg, hB, W3l, b3, W3r, out, NN, mu2, istd2, g2, be2);
}